// Round 1
// baseline (2020.394 us; speedup 1.0000x reference)
//
#include <hip/hip_runtime.h>
#include <math.h>

#define N_NODES 100000
#define N_EDGES 1000000
#define H 64
#define CLS 10
#define G_GRAPHS 64

__global__ void fill_kernel(float* p, float v, int n) {
    int i = blockIdx.x * blockDim.x + threadIdx.x;
    int stride = gridDim.x * blockDim.x;
    for (; i < n; i += stride) p[i] = v;
}

__global__ void deg_kernel(const int* __restrict__ dst, float* __restrict__ deg) {
    int e = blockIdx.x * blockDim.x + threadIdx.x;
    if (e < N_EDGES) atomicAdd(&deg[dst[e]], 1.0f);
}

// feat = h (N x K) @ W (K x H); el = feat @ al; er = feat @ ar
// one wave (64 lanes) per node; 4 nodes per 256-thread block
__global__ void feat_kernel(const float* __restrict__ h, const float* __restrict__ W,
                            const float* __restrict__ al, const float* __restrict__ ar,
                            float* __restrict__ feat, float* __restrict__ el,
                            float* __restrict__ er, int K) {
    __shared__ float Ws[64 * 64];
    __shared__ float als[64], ars[64];
    int tid = threadIdx.x;
    for (int idx = tid; idx < K * H; idx += blockDim.x) Ws[idx] = W[idx];
    if (tid < H) { als[tid] = al[tid]; ars[tid] = ar[tid]; }
    __syncthreads();
    int wave = tid >> 6;
    int lane = tid & 63;
    int node = blockIdx.x * 4 + wave;
    if (node >= N_NODES) return;
    float f = 0.f;
    for (int k = 0; k < K; ++k) f += h[node * K + k] * Ws[k * H + lane];
    feat[node * H + lane] = f;
    float pl = f * als[lane];
    float pr = f * ars[lane];
    for (int off = 32; off > 0; off >>= 1) {
        pl += __shfl_down(pl, off, 64);
        pr += __shfl_down(pr, off, 64);
    }
    if (lane == 0) { el[node] = pl; er[node] = pr; }
}

__device__ inline void atomicMaxFloat(float* addr, float val) {
    if (val >= 0.f) atomicMax((int*)addr, __float_as_int(val));
    else atomicMin((unsigned int*)addr, __float_as_uint(val));
}

__device__ inline float leaky02(float v) { return v >= 0.f ? v : 0.2f * v; }

__global__ void edge_max_kernel(const int* __restrict__ src, const int* __restrict__ dst,
                                const float* __restrict__ el, const float* __restrict__ er,
                                float* __restrict__ m) {
    int e = blockIdx.x * blockDim.x + threadIdx.x;
    if (e >= N_EDGES) return;
    int d = dst[e];
    float v = leaky02(el[src[e]] + er[d]);
    atomicMaxFloat(&m[d], v);
}

__global__ void edge_sum_kernel(const int* __restrict__ src, const int* __restrict__ dst,
                                const float* __restrict__ el, const float* __restrict__ er,
                                const float* __restrict__ m, float* __restrict__ s) {
    int e = blockIdx.x * blockDim.x + threadIdx.x;
    if (e >= N_EDGES) return;
    int d = dst[e];
    float v = leaky02(el[src[e]] + er[d]);
    atomicAdd(&s[d], expf(v - m[d]));
}

// one wave per edge: lane j adds alpha * feat[src][j] into out[dst][j]
__global__ void edge_agg_kernel(const int* __restrict__ src, const int* __restrict__ dst,
                                const float* __restrict__ el, const float* __restrict__ er,
                                const float* __restrict__ m, const float* __restrict__ s,
                                const float* __restrict__ feat, float* __restrict__ out) {
    int wv = (blockIdx.x * blockDim.x + threadIdx.x) >> 6;
    int lane = threadIdx.x & 63;
    if (wv >= N_EDGES) return;
    int sE = src[wv], dE = dst[wv];
    float v = leaky02(el[sE] + er[dE]);
    float alpha = expf(v - m[dE]) / s[dE];
    atomicAdd(&out[dE * H + lane], alpha * feat[sE * H + lane]);
}

__global__ void bias_relu_kernel(float* __restrict__ h, const float* __restrict__ b) {
    int i = blockIdx.x * blockDim.x + threadIdx.x;
    int stride = gridDim.x * blockDim.x;
    for (; i < N_NODES * H; i += stride) {
        float v = h[i] + b[i & 63];
        h[i] = v > 0.f ? v : 0.f;
    }
}

// one wave per node (grid-stride): accumulate into per-graph sums
__global__ void pool_kernel(const float* __restrict__ h, const int* __restrict__ gid,
                            float* __restrict__ hg, float* __restrict__ counts) {
    int gwave = (blockIdx.x * blockDim.x + threadIdx.x) >> 6;
    int lane = threadIdx.x & 63;
    int nwaves = (gridDim.x * blockDim.x) >> 6;
    for (int node = gwave; node < N_NODES; node += nwaves) {
        int g = gid[node];
        if (lane == 0) atomicAdd(&counts[g], 1.0f);
        atomicAdd(&hg[g * H + lane], h[node * H + lane]);
    }
}

__global__ void final_kernel(const float* __restrict__ hg, const float* __restrict__ counts,
                             const float* __restrict__ Wc, const float* __restrict__ bc,
                             float* __restrict__ out) {
    int g = blockIdx.x;
    int c = threadIdx.x;
    if (c >= CLS) return;
    float cnt = fmaxf(counts[g], 1.0f);
    float acc = 0.f;
    for (int j = 0; j < H; ++j) acc += hg[g * H + j] * Wc[j * CLS + c];
    out[g * CLS + c] = acc / cnt + bc[c];
}

extern "C" void kernel_launch(void* const* d_in, const int* in_sizes, int n_in,
                              void* d_out, int out_size, void* d_ws, size_t ws_size,
                              hipStream_t stream) {
    const int* src = (const int*)d_in[0];
    const int* dst = (const int*)d_in[1];
    const int* gid = (const int*)d_in[2];
    const float* W1 = (const float*)d_in[3];
    const float* al1 = (const float*)d_in[4];
    const float* ar1 = (const float*)d_in[5];
    const float* b1 = (const float*)d_in[6];
    const float* W2 = (const float*)d_in[7];
    const float* al2 = (const float*)d_in[8];
    const float* ar2 = (const float*)d_in[9];
    const float* b2 = (const float*)d_in[10];
    const float* W3 = (const float*)d_in[11];
    const float* al3 = (const float*)d_in[12];
    const float* ar3 = (const float*)d_in[13];
    const float* b3 = (const float*)d_in[14];
    const float* Wc = (const float*)d_in[15];
    const float* bc = (const float*)d_in[16];
    float* out = (float*)d_out;

    float* ws = (float*)d_ws;
    float* bufA = ws;                       // N*H  (h / aggregation output)
    float* bufB = bufA + (size_t)N_NODES * H;  // N*H  (feat)
    float* deg = bufB + (size_t)N_NODES * H;   // N
    float* el = deg + N_NODES;              // N
    float* er = el + N_NODES;               // N
    float* m = er + N_NODES;                // N
    float* s = m + N_NODES;                 // N
    float* hg = s + N_NODES;                // G*H
    float* counts = hg + G_GRAPHS * H;      // G

    const float* Warr[3] = {W1, W2, W3};
    const float* alarr[3] = {al1, al2, al3};
    const float* ararr[3] = {ar1, ar2, ar3};
    const float* barr[3] = {b1, b2, b3};

    int eblocks = (N_EDGES + 255) / 256;
    int nblocks4 = (N_NODES + 3) / 4;
    int aggblocks = (N_EDGES * 64 + 255) / 256;  // wave per edge, 4 waves/block

    // degree
    fill_kernel<<<256, 256, 0, stream>>>(deg, 0.f, N_NODES);
    deg_kernel<<<eblocks, 256, 0, stream>>>(dst, deg);

    for (int layer = 0; layer < 3; ++layer) {
        const float* hcur = (layer == 0) ? deg : bufA;
        int K = (layer == 0) ? 1 : H;
        feat_kernel<<<nblocks4, 256, 0, stream>>>(hcur, Warr[layer], alarr[layer],
                                                  ararr[layer], bufB, el, er, K);
        fill_kernel<<<256, 256, 0, stream>>>(m, -INFINITY, N_NODES);
        fill_kernel<<<256, 256, 0, stream>>>(s, 0.f, N_NODES);
        fill_kernel<<<2048, 256, 0, stream>>>(bufA, 0.f, N_NODES * H);
        edge_max_kernel<<<eblocks, 256, 0, stream>>>(src, dst, el, er, m);
        edge_sum_kernel<<<eblocks, 256, 0, stream>>>(src, dst, el, er, m, s);
        edge_agg_kernel<<<aggblocks, 256, 0, stream>>>(src, dst, el, er, m, s, bufB, bufA);
        bias_relu_kernel<<<2048, 256, 0, stream>>>(bufA, barr[layer]);
    }

    // pooling
    fill_kernel<<<1, 256, 0, stream>>>(hg, 0.f, G_GRAPHS * H);
    fill_kernel<<<1, 64, 0, stream>>>(counts, 0.f, G_GRAPHS);
    pool_kernel<<<1024, 256, 0, stream>>>(bufA, gid, hg, counts);
    final_kernel<<<G_GRAPHS, 64, 0, stream>>>(hg, counts, Wc, bc, out);
}

// Round 2
// 1291.462 us; speedup vs baseline: 1.5644x; 1.5644x over previous
//
#include <hip/hip_runtime.h>
#include <math.h>

#define N_NODES 100000
#define N_EDGES 1000000
#define H 64
#define CLS 10
#define G_GRAPHS 64

__global__ void fill_kernel(float* p, float v, int n) {
    int i = blockIdx.x * blockDim.x + threadIdx.x;
    int stride = gridDim.x * blockDim.x;
    for (; i < n; i += stride) p[i] = v;
}

// zero bufA (N*H), set m = -inf, s = 0 in one launch
__global__ void fill_layer_kernel(float* __restrict__ bufA, float* __restrict__ m,
                                  float* __restrict__ s) {
    int i = blockIdx.x * blockDim.x + threadIdx.x;
    int stride = gridDim.x * blockDim.x;
    for (int j = i; j < N_NODES * H; j += stride) bufA[j] = 0.f;
    for (int j = i; j < N_NODES; j += stride) { m[j] = -INFINITY; s[j] = 0.f; }
}

__global__ void deg_kernel(const int* __restrict__ dst, float* __restrict__ deg) {
    int e = blockIdx.x * blockDim.x + threadIdx.x;
    if (e < N_EDGES) atomicAdd(&deg[dst[e]], 1.0f);
}

// feat = h (N x K) @ W (K x H); el = feat @ al; er = feat @ ar
// one wave (64 lanes) per node; 4 nodes per 256-thread block
__global__ void feat_kernel(const float* __restrict__ h, const float* __restrict__ W,
                            const float* __restrict__ al, const float* __restrict__ ar,
                            float* __restrict__ feat, float* __restrict__ el,
                            float* __restrict__ er, int K) {
    __shared__ float Ws[64 * 64];
    __shared__ float als[64], ars[64];
    int tid = threadIdx.x;
    for (int idx = tid; idx < K * H; idx += blockDim.x) Ws[idx] = W[idx];
    if (tid < H) { als[tid] = al[tid]; ars[tid] = ar[tid]; }
    __syncthreads();
    int wave = tid >> 6;
    int lane = tid & 63;
    int node = blockIdx.x * 4 + wave;
    if (node >= N_NODES) return;
    float f = 0.f;
    for (int k = 0; k < K; ++k) f += h[node * K + k] * Ws[k * H + lane];
    feat[node * H + lane] = f;
    float pl = f * als[lane];
    float pr = f * ars[lane];
    for (int off = 32; off > 0; off >>= 1) {
        pl += __shfl_down(pl, off, 64);
        pr += __shfl_down(pr, off, 64);
    }
    if (lane == 0) { el[node] = pl; er[node] = pr; }
}

__device__ inline void atomicMaxFloat(float* addr, float val) {
    if (val >= 0.f) atomicMax((int*)addr, __float_as_int(val));
    else atomicMin((unsigned int*)addr, __float_as_uint(val));
}

__device__ inline float leaky02(float v) { return v >= 0.f ? v : 0.2f * v; }

__global__ void edge_max_kernel(const int* __restrict__ src, const int* __restrict__ dst,
                                const float* __restrict__ el, const float* __restrict__ er,
                                float* __restrict__ m) {
    int e = blockIdx.x * blockDim.x + threadIdx.x;
    if (e >= N_EDGES) return;
    int d = dst[e];
    float v = leaky02(el[src[e]] + er[d]);
    atomicMaxFloat(&m[d], v);
}

__global__ void edge_sum_kernel(const int* __restrict__ src, const int* __restrict__ dst,
                                const float* __restrict__ el, const float* __restrict__ er,
                                const float* __restrict__ m, float* __restrict__ s) {
    int e = blockIdx.x * blockDim.x + threadIdx.x;
    if (e >= N_EDGES) return;
    int d = dst[e];
    float v = leaky02(el[src[e]] + er[d]);
    atomicAdd(&s[d], expf(v - m[d]));
}

// one wave per edge: lane j adds alpha * feat[src][j] into out[dst][j]
__global__ void edge_agg_kernel(const int* __restrict__ src, const int* __restrict__ dst,
                                const float* __restrict__ el, const float* __restrict__ er,
                                const float* __restrict__ m, const float* __restrict__ s,
                                const float* __restrict__ feat, float* __restrict__ out) {
    int wv = (blockIdx.x * blockDim.x + threadIdx.x) >> 6;
    int lane = threadIdx.x & 63;
    if (wv >= N_EDGES) return;
    int sE = src[wv], dE = dst[wv];
    float v = leaky02(el[sE] + er[dE]);
    float alpha = expf(v - m[dE]) / s[dE];
    atomicAdd(&out[dE * H + lane], alpha * feat[sE * H + lane]);
}

__global__ void bias_relu_kernel(float* __restrict__ h, const float* __restrict__ b) {
    int i = blockIdx.x * blockDim.x + threadIdx.x;
    int stride = gridDim.x * blockDim.x;
    for (; i < N_NODES * H; i += stride) {
        float v = h[i] + b[i & 63];
        h[i] = v > 0.f ? v : 0.f;
    }
}

// graph_ids sorted: each wave owns a contiguous node chunk, accumulates per-graph
// partial sums in registers, flushes one atomicAdd per (graph-transition x lane)
#define POOL_WAVES 2048
__global__ void pool_kernel(const float* __restrict__ h, const int* __restrict__ gid,
                            float* __restrict__ hg, float* __restrict__ counts) {
    int gwave = (blockIdx.x * blockDim.x + threadIdx.x) >> 6;
    int lane = threadIdx.x & 63;
    const int chunk = (N_NODES + POOL_WAVES - 1) / POOL_WAVES;
    int start = gwave * chunk;
    int end = min(start + chunk, N_NODES);
    if (start >= end) return;
    int cur_g = gid[start];
    float acc = 0.f;
    float cnt = 0.f;
    for (int node = start; node < end; ++node) {
        int g = gid[node];
        if (g != cur_g) {
            atomicAdd(&hg[cur_g * H + lane], acc);
            if (lane == 0) atomicAdd(&counts[cur_g], cnt);
            acc = 0.f; cnt = 0.f; cur_g = g;
        }
        acc += h[node * H + lane];
        cnt += 1.f;
    }
    atomicAdd(&hg[cur_g * H + lane], acc);
    if (lane == 0) atomicAdd(&counts[cur_g], cnt);
}

__global__ void final_kernel(const float* __restrict__ hg, const float* __restrict__ counts,
                             const float* __restrict__ Wc, const float* __restrict__ bc,
                             float* __restrict__ out) {
    int g = blockIdx.x;
    int c = threadIdx.x;
    if (c >= CLS) return;
    float cnt = fmaxf(counts[g], 1.0f);
    float acc = 0.f;
    for (int j = 0; j < H; ++j) acc += hg[g * H + j] * Wc[j * CLS + c];
    out[g * CLS + c] = acc / cnt + bc[c];
}

extern "C" void kernel_launch(void* const* d_in, const int* in_sizes, int n_in,
                              void* d_out, int out_size, void* d_ws, size_t ws_size,
                              hipStream_t stream) {
    const int* src = (const int*)d_in[0];
    const int* dst = (const int*)d_in[1];
    const int* gid = (const int*)d_in[2];
    const float* W1 = (const float*)d_in[3];
    const float* al1 = (const float*)d_in[4];
    const float* ar1 = (const float*)d_in[5];
    const float* b1 = (const float*)d_in[6];
    const float* W2 = (const float*)d_in[7];
    const float* al2 = (const float*)d_in[8];
    const float* ar2 = (const float*)d_in[9];
    const float* b2 = (const float*)d_in[10];
    const float* W3 = (const float*)d_in[11];
    const float* al3 = (const float*)d_in[12];
    const float* ar3 = (const float*)d_in[13];
    const float* b3 = (const float*)d_in[14];
    const float* Wc = (const float*)d_in[15];
    const float* bc = (const float*)d_in[16];
    float* out = (float*)d_out;

    float* ws = (float*)d_ws;
    float* bufA = ws;                          // N*H  (h / aggregation output)
    float* bufB = bufA + (size_t)N_NODES * H;  // N*H  (feat)
    float* deg = bufB + (size_t)N_NODES * H;   // N
    float* el = deg + N_NODES;                 // N
    float* er = el + N_NODES;                  // N
    float* m = er + N_NODES;                   // N
    float* s = m + N_NODES;                    // N
    float* hg = s + N_NODES;                   // G*H
    float* counts = hg + G_GRAPHS * H;         // G

    const float* Warr[3] = {W1, W2, W3};
    const float* alarr[3] = {al1, al2, al3};
    const float* ararr[3] = {ar1, ar2, ar3};
    const float* barr[3] = {b1, b2, b3};

    int eblocks = (N_EDGES + 255) / 256;
    int nblocks4 = (N_NODES + 3) / 4;
    int aggblocks = (N_EDGES * 64 + 255) / 256;  // wave per edge, 4 waves/block

    // degree
    fill_kernel<<<256, 256, 0, stream>>>(deg, 0.f, N_NODES);
    deg_kernel<<<eblocks, 256, 0, stream>>>(dst, deg);

    for (int layer = 0; layer < 3; ++layer) {
        const float* hcur = (layer == 0) ? deg : bufA;
        int K = (layer == 0) ? 1 : H;
        feat_kernel<<<nblocks4, 256, 0, stream>>>(hcur, Warr[layer], alarr[layer],
                                                  ararr[layer], bufB, el, er, K);
        fill_layer_kernel<<<2048, 256, 0, stream>>>(bufA, m, s);
        edge_max_kernel<<<eblocks, 256, 0, stream>>>(src, dst, el, er, m);
        edge_sum_kernel<<<eblocks, 256, 0, stream>>>(src, dst, el, er, m, s);
        edge_agg_kernel<<<aggblocks, 256, 0, stream>>>(src, dst, el, er, m, s, bufB, bufA);
        bias_relu_kernel<<<2048, 256, 0, stream>>>(bufA, barr[layer]);
    }

    // pooling
    fill_kernel<<<1, 256, 0, stream>>>(hg, 0.f, G_GRAPHS * H);
    fill_kernel<<<1, 64, 0, stream>>>(counts, 0.f, G_GRAPHS);
    pool_kernel<<<POOL_WAVES / 4, 256, 0, stream>>>(bufA, gid, hg, counts);
    final_kernel<<<G_GRAPHS, 64, 0, stream>>>(hg, counts, Wc, bc, out);
}

// Round 4
// 787.398 us; speedup vs baseline: 2.5659x; 1.6402x over previous
//
#include <hip/hip_runtime.h>
#include <math.h>

#define N_NODES 100000
#define N_EDGES 1000000
#define H 64
#define CLS 10
#define G_GRAPHS 64
#define SCAN_CHUNK 1024
#define NB ((N_NODES + SCAN_CHUNK - 1) / SCAN_CHUNK)   // 98

__global__ void fill_f_kernel(float* p, float v, int n) {
    int i = blockIdx.x * blockDim.x + threadIdx.x;
    int stride = gridDim.x * blockDim.x;
    for (; i < n; i += stride) p[i] = v;
}

__global__ void fill_i_kernel(int* p, int v, int n) {
    int i = blockIdx.x * blockDim.x + threadIdx.x;
    int stride = gridDim.x * blockDim.x;
    for (; i < n; i += stride) p[i] = v;
}

__global__ void count_kernel(const int* __restrict__ dst, int* __restrict__ cnt) {
    int e = blockIdx.x * blockDim.x + threadIdx.x;
    if (e < N_EDGES) atomicAdd(&cnt[dst[e]], 1);
}

// per-block sums of 1024-element chunks
__global__ void scanA_kernel(const int* __restrict__ cnt, int* __restrict__ bsum) {
    __shared__ int lds[256];
    int b = blockIdx.x, tid = threadIdx.x;
    int base = b * SCAN_CHUNK + tid * 4;
    int s = 0;
    for (int j = 0; j < 4; ++j) {
        int idx = base + j;
        if (idx < N_NODES) s += cnt[idx];
    }
    lds[tid] = s;
    __syncthreads();
    for (int off = 128; off > 0; off >>= 1) {
        if (tid < off) lds[tid] += lds[tid + off];
        __syncthreads();
    }
    if (tid == 0) bsum[b] = lds[0];
}

// exclusive scan of the NB block sums (single thread; NB=98)
__global__ void scanB_kernel(const int* __restrict__ bsum, int* __restrict__ boff) {
    if (threadIdx.x == 0 && blockIdx.x == 0) {
        int acc = 0;
        for (int i = 0; i < NB; ++i) { boff[i] = acc; acc += bsum[i]; }
    }
}

// block-local inclusive scan + block offset -> row_off (exclusive over cnt)
__global__ void scanC_kernel(const int* __restrict__ cnt, const int* __restrict__ boff,
                             int* __restrict__ row_off) {
    __shared__ int lds[256];
    int b = blockIdx.x, tid = threadIdx.x;
    int base = b * SCAN_CHUNK + tid * 4;
    int v[4];
    for (int j = 0; j < 4; ++j) {
        int idx = base + j;
        v[j] = (idx < N_NODES) ? cnt[idx] : 0;
    }
    // local inclusive
    v[1] += v[0]; v[2] += v[1]; v[3] += v[2];
    lds[tid] = v[3];
    __syncthreads();
    // Hillis-Steele inclusive scan over 256 thread-totals
    for (int off = 1; off < 256; off <<= 1) {
        int t = (tid >= off) ? lds[tid - off] : 0;
        __syncthreads();
        lds[tid] += t;
        __syncthreads();
    }
    int prev = (tid > 0) ? lds[tid - 1] : 0;
    int offset = boff[b] + prev;
    for (int j = 0; j < 4; ++j) {
        int idx = base + j;
        if (idx < N_NODES) row_off[idx + 1] = offset + v[j];
    }
    if (b == 0 && tid == 0) row_off[0] = 0;
}

__global__ void scatter_kernel(const int* __restrict__ src, const int* __restrict__ dst,
                               const int* __restrict__ row_off, int* __restrict__ cursor,
                               int* __restrict__ csr_src) {
    int e = blockIdx.x * blockDim.x + threadIdx.x;
    if (e >= N_EDGES) return;
    int d = dst[e];
    int pos = row_off[d] + atomicAdd(&cursor[d], 1);
    csr_src[pos] = src[e];
}

__device__ inline float leaky02(float v) { return v >= 0.f ? v : 0.2f * v; }

// feat = h (N x K) @ W (K x H); el = feat @ al; er = feat @ ar
// one wave per node; K==1 uses degree from row_off as h
__global__ void feat_kernel(const float* __restrict__ h, const int* __restrict__ row_off,
                            const float* __restrict__ W,
                            const float* __restrict__ al, const float* __restrict__ ar,
                            float* __restrict__ feat, float* __restrict__ el,
                            float* __restrict__ er, int K) {
    __shared__ float Ws[64 * 64];
    __shared__ float als[64], ars[64];
    int tid = threadIdx.x;
    for (int idx = tid; idx < K * H; idx += blockDim.x) Ws[idx] = W[idx];
    if (tid < H) { als[tid] = al[tid]; ars[tid] = ar[tid]; }
    __syncthreads();
    int wave = tid >> 6;
    int lane = tid & 63;
    int node = blockIdx.x * 4 + wave;
    if (node >= N_NODES) return;
    float f;
    if (K == 1) {
        float d = (float)(row_off[node + 1] - row_off[node]);
        f = d * Ws[lane];
    } else {
        float hval = h[node * H + lane];   // coalesced
        f = 0.f;
        #pragma unroll 16
        for (int k = 0; k < 64; ++k) f += __shfl(hval, k, 64) * Ws[k * H + lane];
    }
    feat[node * H + lane] = f;
    float pl = f * als[lane];
    float pr = f * ars[lane];
    for (int off = 32; off > 0; off >>= 1) {
        pl += __shfl_down(pl, off, 64);
        pr += __shfl_down(pr, off, 64);
    }
    if (lane == 0) { el[node] = pl; er[node] = pr; }
}

// fused softmax + aggregation + bias + relu; one wave per dst node
__global__ void gat_gather_kernel(const int* __restrict__ row_off, const int* __restrict__ csr_src,
                                  const float* __restrict__ el, const float* __restrict__ er,
                                  const float* __restrict__ feat, const float* __restrict__ b,
                                  float* __restrict__ out) {
    int wv = (blockIdx.x * blockDim.x + threadIdx.x) >> 6;
    int lane = threadIdx.x & 63;
    if (wv >= N_NODES) return;
    int beg = row_off[wv], end = row_off[wv + 1];
    float ern = er[wv];
    // pass A: running max (lane-parallel over edges)
    float lm = -INFINITY;
    for (int i = beg + lane; i < end; i += 64)
        lm = fmaxf(lm, leaky02(el[csr_src[i]] + ern));
    for (int off = 32; off > 0; off >>= 1)
        lm = fmaxf(lm, __shfl_xor(lm, off, 64));
    // pass A2: exp-sum
    float ls = 0.f;
    for (int i = beg + lane; i < end; i += 64)
        ls += expf(leaky02(el[csr_src[i]] + ern) - lm);
    for (int off = 32; off > 0; off >>= 1)
        ls += __shfl_xor(ls, off, 64);
    // pass B: weighted feature gather (serial over edges, coalesced 256B per edge)
    float acc = 0.f;
    for (int i = beg; i < end; ++i) {
        int sE = csr_src[i];
        float w = expf(leaky02(el[sE] + ern) - lm);
        acc += w * feat[sE * H + lane];
    }
    float val = (end > beg) ? (acc / ls) : 0.f;
    val += b[lane];
    out[wv * H + lane] = val > 0.f ? val : 0.f;
}

// graph_ids sorted: wave-chunked register accumulation, atomics only at transitions
#define POOL_WAVES 2048
__global__ void pool_kernel(const float* __restrict__ h, const int* __restrict__ gid,
                            float* __restrict__ hg, float* __restrict__ counts) {
    int gwave = (blockIdx.x * blockDim.x + threadIdx.x) >> 6;
    int lane = threadIdx.x & 63;
    const int chunk = (N_NODES + POOL_WAVES - 1) / POOL_WAVES;
    int start = gwave * chunk;
    int end = min(start + chunk, N_NODES);
    if (start >= end) return;
    int cur_g = gid[start];
    float acc = 0.f;
    float cnt = 0.f;
    for (int node = start; node < end; ++node) {
        int g = gid[node];
        if (g != cur_g) {
            atomicAdd(&hg[cur_g * H + lane], acc);
            if (lane == 0) atomicAdd(&counts[cur_g], cnt);
            acc = 0.f; cnt = 0.f; cur_g = g;
        }
        acc += h[node * H + lane];
        cnt += 1.f;
    }
    atomicAdd(&hg[cur_g * H + lane], acc);
    if (lane == 0) atomicAdd(&counts[cur_g], cnt);
}

__global__ void final_kernel(const float* __restrict__ hg, const float* __restrict__ counts,
                             const float* __restrict__ Wc, const float* __restrict__ bc,
                             float* __restrict__ out) {
    int g = blockIdx.x;
    int c = threadIdx.x;
    if (c >= CLS) return;
    float cnt = fmaxf(counts[g], 1.0f);
    float acc = 0.f;
    for (int j = 0; j < H; ++j) acc += hg[g * H + j] * Wc[j * CLS + c];
    out[g * CLS + c] = acc / cnt + bc[c];
}

extern "C" void kernel_launch(void* const* d_in, const int* in_sizes, int n_in,
                              void* d_out, int out_size, void* d_ws, size_t ws_size,
                              hipStream_t stream) {
    const int* src = (const int*)d_in[0];
    const int* dst = (const int*)d_in[1];
    const int* gid = (const int*)d_in[2];
    const float* W1 = (const float*)d_in[3];
    const float* al1 = (const float*)d_in[4];
    const float* ar1 = (const float*)d_in[5];
    const float* b1 = (const float*)d_in[6];
    const float* W2 = (const float*)d_in[7];
    const float* al2 = (const float*)d_in[8];
    const float* ar2 = (const float*)d_in[9];
    const float* b2 = (const float*)d_in[10];
    const float* W3 = (const float*)d_in[11];
    const float* al3 = (const float*)d_in[12];
    const float* ar3 = (const float*)d_in[13];
    const float* b3 = (const float*)d_in[14];
    const float* Wc = (const float*)d_in[15];
    const float* bc = (const float*)d_in[16];
    float* out = (float*)d_out;

    float* ws = (float*)d_ws;
    float* bufA = ws;                          // N*H  (h)
    float* bufB = bufA + (size_t)N_NODES * H;  // N*H  (feat)
    float* el = bufB + (size_t)N_NODES * H;    // N
    float* er = el + N_NODES;                  // N
    float* hg = er + N_NODES;                  // G*H
    float* counts = hg + G_GRAPHS * H;         // G
    int* row_off = (int*)(counts + G_GRAPHS);  // N+1
    int* cnt = row_off + N_NODES + 1;          // N
    int* bsum = cnt + N_NODES;                 // NB
    int* boff = bsum + NB;                     // NB
    int* csr_src = boff + NB;                  // E

    const float* Warr[3] = {W1, W2, W3};
    const float* alarr[3] = {al1, al2, al3};
    const float* ararr[3] = {ar1, ar2, ar3};
    const float* barr[3] = {b1, b2, b3};

    int eblocks = (N_EDGES + 255) / 256;
    int nblocks4 = (N_NODES + 3) / 4;

    // ---- build CSR by dst ----
    fill_i_kernel<<<256, 256, 0, stream>>>(cnt, 0, N_NODES);
    count_kernel<<<eblocks, 256, 0, stream>>>(dst, cnt);
    scanA_kernel<<<NB, 256, 0, stream>>>(cnt, bsum);
    scanB_kernel<<<1, 64, 0, stream>>>(bsum, boff);
    scanC_kernel<<<NB, 256, 0, stream>>>(cnt, boff, row_off);
    fill_i_kernel<<<256, 256, 0, stream>>>(cnt, 0, N_NODES);
    scatter_kernel<<<eblocks, 256, 0, stream>>>(src, dst, row_off, cnt, csr_src);

    // ---- 3 GAT layers ----
    for (int layer = 0; layer < 3; ++layer) {
        int K = (layer == 0) ? 1 : H;
        feat_kernel<<<nblocks4, 256, 0, stream>>>(bufA, row_off, Warr[layer], alarr[layer],
                                                  ararr[layer], bufB, el, er, K);
        gat_gather_kernel<<<nblocks4, 256, 0, stream>>>(row_off, csr_src, el, er, bufB,
                                                        barr[layer], bufA);
    }

    // ---- pooling + classifier ----
    fill_f_kernel<<<1, 256, 0, stream>>>(hg, 0.f, G_GRAPHS * H + G_GRAPHS);
    pool_kernel<<<POOL_WAVES / 4, 256, 0, stream>>>(bufA, gid, hg, counts);
    final_kernel<<<G_GRAPHS, 64, 0, stream>>>(hg, counts, Wc, bc, out);
}

// Round 6
// 494.763 us; speedup vs baseline: 4.0836x; 1.5915x over previous
//
#include <hip/hip_runtime.h>
#include <math.h>

#define N_NODES 100000
#define N_EDGES 1000000
#define H 64
#define CLS 10
#define G_GRAPHS 64
#define SCAN_CHUNK 1024
#define NB ((N_NODES + SCAN_CHUNK - 1) / SCAN_CHUNK)   // 98

__global__ void fill_f_kernel(float* p, float v, int n) {
    int i = blockIdx.x * blockDim.x + threadIdx.x;
    int stride = gridDim.x * blockDim.x;
    for (; i < n; i += stride) p[i] = v;
}

__global__ void fill_i_kernel(int* p, int v, int n) {
    int i = blockIdx.x * blockDim.x + threadIdx.x;
    int stride = gridDim.x * blockDim.x;
    for (; i < n; i += stride) p[i] = v;
}

__global__ void count_kernel(const int* __restrict__ dst, int* __restrict__ cnt) {
    int e = blockIdx.x * blockDim.x + threadIdx.x;
    if (e < N_EDGES) atomicAdd(&cnt[dst[e]], 1);
}

// per-block sums of 1024-element chunks
__global__ void scanA_kernel(const int* __restrict__ cnt, int* __restrict__ bsum) {
    __shared__ int lds[256];
    int b = blockIdx.x, tid = threadIdx.x;
    int base = b * SCAN_CHUNK + tid * 4;
    int s = 0;
    for (int j = 0; j < 4; ++j) {
        int idx = base + j;
        if (idx < N_NODES) s += cnt[idx];
    }
    lds[tid] = s;
    __syncthreads();
    for (int off = 128; off > 0; off >>= 1) {
        if (tid < off) lds[tid] += lds[tid + off];
        __syncthreads();
    }
    if (tid == 0) bsum[b] = lds[0];
}

// block-local scan + (inline) exclusive scan of bsum -> row_off; also re-zeroes cnt
__global__ void scanC_kernel(int* __restrict__ cnt, const int* __restrict__ bsum,
                             int* __restrict__ row_off) {
    __shared__ int lds[256];
    __shared__ int boff_s;
    int b = blockIdx.x, tid = threadIdx.x;
    if (tid == 0) {
        int acc = 0;
        for (int i = 0; i < b; ++i) acc += bsum[i];
        boff_s = acc;
    }
    int base = b * SCAN_CHUNK + tid * 4;
    int v[4];
    for (int j = 0; j < 4; ++j) {
        int idx = base + j;
        v[j] = (idx < N_NODES) ? cnt[idx] : 0;
        if (idx < N_NODES) cnt[idx] = 0;   // cursor for scatter
    }
    v[1] += v[0]; v[2] += v[1]; v[3] += v[2];
    lds[tid] = v[3];
    __syncthreads();
    for (int off = 1; off < 256; off <<= 1) {
        int t = (tid >= off) ? lds[tid - off] : 0;
        __syncthreads();
        lds[tid] += t;
        __syncthreads();
    }
    int prev = (tid > 0) ? lds[tid - 1] : 0;
    int offset = boff_s + prev;
    for (int j = 0; j < 4; ++j) {
        int idx = base + j;
        if (idx < N_NODES) row_off[idx + 1] = offset + v[j];
    }
    if (b == 0 && tid == 0) row_off[0] = 0;
}

__global__ void scatter_kernel(const int* __restrict__ src, const int* __restrict__ dst,
                               const int* __restrict__ row_off, int* __restrict__ cursor,
                               int* __restrict__ csr_src) {
    int e = blockIdx.x * blockDim.x + threadIdx.x;
    if (e >= N_EDGES) return;
    int d = dst[e];
    int pos = row_off[d] + atomicAdd(&cursor[d], 1);
    csr_src[pos] = src[e];
}

__device__ inline float leaky02(float v) { return v >= 0.f ? v : 0.2f * v; }

// layer-0 feat: h = deg (from row_off), W is 1 x H
__global__ void feat1_kernel(const int* __restrict__ row_off, const float* __restrict__ W,
                             const float* __restrict__ al, const float* __restrict__ ar,
                             float* __restrict__ feat, float* __restrict__ el,
                             float* __restrict__ er) {
    int wv = (blockIdx.x * blockDim.x + threadIdx.x) >> 6;
    int lane = threadIdx.x & 63;
    if (wv >= N_NODES) return;
    float d = (float)(row_off[wv + 1] - row_off[wv]);
    float f = d * W[lane];
    feat[wv * H + lane] = f;
    float pl = f * al[lane];
    float pr = f * ar[lane];
    for (int off = 32; off > 0; off >>= 1) {
        pl += __shfl_down(pl, off, 64);
        pr += __shfl_down(pr, off, 64);
    }
    if (lane == 0) { el[wv] = pl; er[wv] = pr; }
}

// feat = h (N x 64) @ W (64 x 64); W column held in 64 VGPRs per lane,
// h rows staged in LDS (broadcast reads), 4 nodes per wave for ILP.
// 16 nodes per 256-thread block; N_NODES % 16 == 0.
__global__ void feat64_kernel(const float* __restrict__ h, const float* __restrict__ W,
                              const float* __restrict__ al, const float* __restrict__ ar,
                              float* __restrict__ feat, float* __restrict__ el,
                              float* __restrict__ er) {
    __shared__ float Wl[64 * 64];
    __shared__ float hs[16 * 64];
    __shared__ float als[64], ars[64];
    int tid = threadIdx.x;
    int nbase = blockIdx.x * 16;
    for (int idx = tid; idx < 64 * 64; idx += 256) Wl[idx] = W[idx];
    for (int idx = tid; idx < 16 * 64; idx += 256) hs[idx] = h[nbase * 64 + idx];
    if (tid < 64) { als[tid] = al[tid]; ars[tid] = ar[tid]; }
    __syncthreads();
    int wave = tid >> 6;
    int lane = tid & 63;
    float wc[64];
    #pragma unroll
    for (int k = 0; k < 64; ++k) wc[k] = Wl[k * 64 + lane];
    const int hb = wave * 4 * 64;
    float a0 = 0.f, a1 = 0.f, a2 = 0.f, a3 = 0.f;
    #pragma unroll
    for (int k = 0; k < 64; ++k) {
        float w_ = wc[k];
        a0 = fmaf(hs[hb + k], w_, a0);
        a1 = fmaf(hs[hb + 64 + k], w_, a1);
        a2 = fmaf(hs[hb + 128 + k], w_, a2);
        a3 = fmaf(hs[hb + 192 + k], w_, a3);
    }
    int n0 = nbase + wave * 4;
    feat[(n0 + 0) * H + lane] = a0;
    feat[(n0 + 1) * H + lane] = a1;
    feat[(n0 + 2) * H + lane] = a2;
    feat[(n0 + 3) * H + lane] = a3;
    float av[4] = {a0, a1, a2, a3};
    #pragma unroll
    for (int j = 0; j < 4; ++j) {
        float pl = av[j] * als[lane];
        float pr = av[j] * ars[lane];
        for (int off = 32; off > 0; off >>= 1) {
            pl += __shfl_down(pl, off, 64);
            pr += __shfl_down(pr, off, 64);
        }
        if (lane == 0) { el[n0 + j] = pl; er[n0 + j] = pr; }
    }
}

// fused softmax + aggregation + bias + relu; one wave per dst node.
// Edge data (src id, weight) kept in registers, broadcast via shfl in pass B.
__global__ void gat_gather_kernel(const int* __restrict__ row_off, const int* __restrict__ csr_src,
                                  const float* __restrict__ el, const float* __restrict__ er,
                                  const float* __restrict__ feat, const float* __restrict__ b,
                                  float* __restrict__ out) {
    int wv = (blockIdx.x * blockDim.x + threadIdx.x) >> 6;
    int lane = threadIdx.x & 63;
    if (wv >= N_NODES) return;
    int beg = row_off[wv], end = row_off[wv + 1];
    int deg = end - beg;
    float ern = er[wv];
    int i0 = beg + lane;
    int s0 = (lane < deg) ? csr_src[i0] : 0;
    float e0 = (lane < deg) ? leaky02(el[s0] + ern) : -INFINITY;
    float lm = e0;
    for (int i = i0 + 64; i < end; i += 64)            // rare: deg > 64
        lm = fmaxf(lm, leaky02(el[csr_src[i]] + ern));
    for (int off = 32; off > 0; off >>= 1)
        lm = fmaxf(lm, __shfl_xor(lm, off, 64));
    float w0 = (lane < deg) ? __expf(e0 - lm) : 0.f;
    float ls = w0;
    for (int i = i0 + 64; i < end; i += 64)            // rare
        ls += __expf(leaky02(el[csr_src[i]] + ern) - lm);
    for (int off = 32; off > 0; off >>= 1)
        ls += __shfl_xor(ls, off, 64);
    float acc = 0.f;
    int dmain = deg < 64 ? deg : 64;
    for (int ii = 0; ii < dmain; ++ii) {
        int sE = __shfl(s0, ii, 64);
        float w = __shfl(w0, ii, 64);
        acc = fmaf(w, feat[sE * H + lane], acc);
    }
    for (int ii = 64; ii < deg; ++ii) {                // rare
        int sE = csr_src[beg + ii];
        float w = __expf(leaky02(el[sE] + ern) - lm);
        acc = fmaf(w, feat[sE * H + lane], acc);
    }
    float val = (deg > 0) ? (acc / ls) : 0.f;
    val += b[lane];
    out[wv * H + lane] = fmaxf(val, 0.f);
}

// graph_ids sorted: wave-chunked register accumulation, atomics only at transitions
#define POOL_WAVES 2048
__global__ void pool_kernel(const float* __restrict__ h, const int* __restrict__ gid,
                            float* __restrict__ hg, float* __restrict__ counts) {
    int gwave = (blockIdx.x * blockDim.x + threadIdx.x) >> 6;
    int lane = threadIdx.x & 63;
    const int chunk = (N_NODES + POOL_WAVES - 1) / POOL_WAVES;
    int start = gwave * chunk;
    int end = min(start + chunk, N_NODES);
    if (start >= end) return;
    int cur_g = gid[start];
    float acc = 0.f;
    float cnt = 0.f;
    for (int node = start; node < end; ++node) {
        int g = gid[node];
        if (g != cur_g) {
            atomicAdd(&hg[cur_g * H + lane], acc);
            if (lane == 0) atomicAdd(&counts[cur_g], cnt);
            acc = 0.f; cnt = 0.f; cur_g = g;
        }
        acc += h[node * H + lane];
        cnt += 1.f;
    }
    atomicAdd(&hg[cur_g * H + lane], acc);
    if (lane == 0) atomicAdd(&counts[cur_g], cnt);
}

__global__ void final_kernel(const float* __restrict__ hg, const float* __restrict__ counts,
                             const float* __restrict__ Wc, const float* __restrict__ bc,
                             float* __restrict__ out) {
    int g = blockIdx.x;
    int c = threadIdx.x;
    if (c >= CLS) return;
    float cnt = fmaxf(counts[g], 1.0f);
    float acc = 0.f;
    for (int j = 0; j < H; ++j) acc += hg[g * H + j] * Wc[j * CLS + c];
    out[g * CLS + c] = acc / cnt + bc[c];
}

extern "C" void kernel_launch(void* const* d_in, const int* in_sizes, int n_in,
                              void* d_out, int out_size, void* d_ws, size_t ws_size,
                              hipStream_t stream) {
    const int* src = (const int*)d_in[0];
    const int* dst = (const int*)d_in[1];
    const int* gid = (const int*)d_in[2];
    const float* W1 = (const float*)d_in[3];
    const float* al1 = (const float*)d_in[4];
    const float* ar1 = (const float*)d_in[5];
    const float* b1 = (const float*)d_in[6];
    const float* W2 = (const float*)d_in[7];
    const float* al2 = (const float*)d_in[8];
    const float* ar2 = (const float*)d_in[9];
    const float* b2 = (const float*)d_in[10];
    const float* W3 = (const float*)d_in[11];
    const float* al3 = (const float*)d_in[12];
    const float* ar3 = (const float*)d_in[13];
    const float* b3 = (const float*)d_in[14];
    const float* Wc = (const float*)d_in[15];
    const float* bc = (const float*)d_in[16];
    float* out = (float*)d_out;

    float* ws = (float*)d_ws;
    float* bufA = ws;                          // N*H  (h)
    float* bufB = bufA + (size_t)N_NODES * H;  // N*H  (feat)
    float* el = bufB + (size_t)N_NODES * H;    // N
    float* er = el + N_NODES;                  // N
    float* hg = er + N_NODES;                  // G*H
    float* counts = hg + G_GRAPHS * H;         // G
    int* row_off = (int*)(counts + G_GRAPHS);  // N+1
    int* cnt = row_off + N_NODES + 1;          // N
    int* bsum = cnt + N_NODES;                 // NB
    int* csr_src = bsum + NB;                  // E

    const float* Warr[3] = {W1, W2, W3};
    const float* alarr[3] = {al1, al2, al3};
    const float* ararr[3] = {ar1, ar2, ar3};
    const float* barr[3] = {b1, b2, b3};

    int eblocks = (N_EDGES + 255) / 256;
    int nblocks4 = (N_NODES + 3) / 4;

    // ---- build CSR by dst ----
    fill_i_kernel<<<256, 256, 0, stream>>>(cnt, 0, N_NODES);
    count_kernel<<<eblocks, 256, 0, stream>>>(dst, cnt);
    scanA_kernel<<<NB, 256, 0, stream>>>(cnt, bsum);
    scanC_kernel<<<NB, 256, 0, stream>>>(cnt, bsum, row_off);
    scatter_kernel<<<eblocks, 256, 0, stream>>>(src, dst, row_off, cnt, csr_src);

    // ---- 3 GAT layers ----
    for (int layer = 0; layer < 3; ++layer) {
        if (layer == 0) {
            feat1_kernel<<<nblocks4, 256, 0, stream>>>(row_off, Warr[0], alarr[0],
                                                       ararr[0], bufB, el, er);
        } else {
            feat64_kernel<<<N_NODES / 16, 256, 0, stream>>>(bufA, Warr[layer], alarr[layer],
                                                            ararr[layer], bufB, el, er);
        }
        gat_gather_kernel<<<nblocks4, 256, 0, stream>>>(row_off, csr_src, el, er, bufB,
                                                        barr[layer], bufA);
    }

    // ---- pooling + classifier ----
    fill_f_kernel<<<1, 256, 0, stream>>>(hg, 0.f, G_GRAPHS * H + G_GRAPHS);
    pool_kernel<<<POOL_WAVES / 4, 256, 0, stream>>>(bufA, gid, hg, counts);
    final_kernel<<<G_GRAPHS, 64, 0, stream>>>(hg, counts, Wc, bc, out);
}

// Round 7
// 400.151 us; speedup vs baseline: 5.0491x; 1.2364x over previous
//
#include <hip/hip_runtime.h>
#include <math.h>

#define N_NODES 100000
#define N_EDGES 1000000
#define H 64
#define CLS 10
#define G_GRAPHS 64
#define SCAN_CHUNK 1024
#define NB ((N_NODES + SCAN_CHUNK - 1) / SCAN_CHUNK)   // 98

__global__ void fill_f_kernel(float* p, float v, int n) {
    int i = blockIdx.x * blockDim.x + threadIdx.x;
    int stride = gridDim.x * blockDim.x;
    for (; i < n; i += stride) p[i] = v;
}

__global__ void fill_i_kernel(int* p, int v, int n) {
    int i = blockIdx.x * blockDim.x + threadIdx.x;
    int stride = gridDim.x * blockDim.x;
    for (; i < n; i += stride) p[i] = v;
}

__global__ void count_kernel(const int* __restrict__ dst, int* __restrict__ cnt) {
    int e = blockIdx.x * blockDim.x + threadIdx.x;
    if (e < N_EDGES) atomicAdd(&cnt[dst[e]], 1);
}

// per-block sums of 1024-element chunks
__global__ void scanA_kernel(const int* __restrict__ cnt, int* __restrict__ bsum) {
    __shared__ int lds[256];
    int b = blockIdx.x, tid = threadIdx.x;
    int base = b * SCAN_CHUNK + tid * 4;
    int s = 0;
    for (int j = 0; j < 4; ++j) {
        int idx = base + j;
        if (idx < N_NODES) s += cnt[idx];
    }
    lds[tid] = s;
    __syncthreads();
    for (int off = 128; off > 0; off >>= 1) {
        if (tid < off) lds[tid] += lds[tid + off];
        __syncthreads();
    }
    if (tid == 0) bsum[b] = lds[0];
}

// block-local scan + (inline) exclusive scan of bsum -> row_off; also re-zeroes cnt
__global__ void scanC_kernel(int* __restrict__ cnt, const int* __restrict__ bsum,
                             int* __restrict__ row_off) {
    __shared__ int lds[256];
    __shared__ int boff_s;
    int b = blockIdx.x, tid = threadIdx.x;
    if (tid == 0) {
        int acc = 0;
        for (int i = 0; i < b; ++i) acc += bsum[i];
        boff_s = acc;
    }
    int base = b * SCAN_CHUNK + tid * 4;
    int v[4];
    for (int j = 0; j < 4; ++j) {
        int idx = base + j;
        v[j] = (idx < N_NODES) ? cnt[idx] : 0;
        if (idx < N_NODES) cnt[idx] = 0;   // cursor for scatter
    }
    v[1] += v[0]; v[2] += v[1]; v[3] += v[2];
    lds[tid] = v[3];
    __syncthreads();
    for (int off = 1; off < 256; off <<= 1) {
        int t = (tid >= off) ? lds[tid - off] : 0;
        __syncthreads();
        lds[tid] += t;
        __syncthreads();
    }
    int prev = (tid > 0) ? lds[tid - 1] : 0;
    int offset = boff_s + prev;
    for (int j = 0; j < 4; ++j) {
        int idx = base + j;
        if (idx < N_NODES) row_off[idx + 1] = offset + v[j];
    }
    if (b == 0 && tid == 0) row_off[0] = 0;
}

__global__ void scatter_kernel(const int* __restrict__ src, const int* __restrict__ dst,
                               const int* __restrict__ row_off, int* __restrict__ cursor,
                               int* __restrict__ csr_src) {
    int e = blockIdx.x * blockDim.x + threadIdx.x;
    if (e >= N_EDGES) return;
    int d = dst[e];
    int pos = row_off[d] + atomicAdd(&cursor[d], 1);
    csr_src[pos] = src[e];
}

__device__ inline float leaky02(float v) { return v >= 0.f ? v : 0.2f * v; }

// layer-0 feat: h = deg (from row_off), W is 1 x H
__global__ void feat1_kernel(const int* __restrict__ row_off, const float* __restrict__ W,
                             const float* __restrict__ al, const float* __restrict__ ar,
                             float* __restrict__ feat, float* __restrict__ el,
                             float* __restrict__ er) {
    int wv = (blockIdx.x * blockDim.x + threadIdx.x) >> 6;
    int lane = threadIdx.x & 63;
    if (wv >= N_NODES) return;
    float d = (float)(row_off[wv + 1] - row_off[wv]);
    float f = d * W[lane];
    feat[wv * H + lane] = f;
    float pl = f * al[lane];
    float pr = f * ar[lane];
    for (int off = 32; off > 0; off >>= 1) {
        pl += __shfl_down(pl, off, 64);
        pr += __shfl_down(pr, off, 64);
    }
    if (lane == 0) { el[wv] = pl; er[wv] = pr; }
}

// feat = h (N x 64) @ W (64 x 64); W column held in 64 VGPRs per lane,
// h rows staged in LDS (broadcast reads), 4 nodes per wave for ILP.
__global__ void feat64_kernel(const float* __restrict__ h, const float* __restrict__ W,
                              const float* __restrict__ al, const float* __restrict__ ar,
                              float* __restrict__ feat, float* __restrict__ el,
                              float* __restrict__ er) {
    __shared__ float Wl[64 * 64];
    __shared__ float hs[16 * 64];
    __shared__ float als[64], ars[64];
    int tid = threadIdx.x;
    int nbase = blockIdx.x * 16;
    for (int idx = tid; idx < 64 * 64; idx += 256) Wl[idx] = W[idx];
    for (int idx = tid; idx < 16 * 64; idx += 256) hs[idx] = h[nbase * 64 + idx];
    if (tid < 64) { als[tid] = al[tid]; ars[tid] = ar[tid]; }
    __syncthreads();
    int wave = tid >> 6;
    int lane = tid & 63;
    float wc[64];
    #pragma unroll
    for (int k = 0; k < 64; ++k) wc[k] = Wl[k * 64 + lane];
    const int hb = wave * 4 * 64;
    float a0 = 0.f, a1 = 0.f, a2 = 0.f, a3 = 0.f;
    #pragma unroll
    for (int k = 0; k < 64; ++k) {
        float w_ = wc[k];
        a0 = fmaf(hs[hb + k], w_, a0);
        a1 = fmaf(hs[hb + 64 + k], w_, a1);
        a2 = fmaf(hs[hb + 128 + k], w_, a2);
        a3 = fmaf(hs[hb + 192 + k], w_, a3);
    }
    int n0 = nbase + wave * 4;
    feat[(n0 + 0) * H + lane] = a0;
    feat[(n0 + 1) * H + lane] = a1;
    feat[(n0 + 2) * H + lane] = a2;
    feat[(n0 + 3) * H + lane] = a3;
    float av[4] = {a0, a1, a2, a3};
    #pragma unroll
    for (int j = 0; j < 4; ++j) {
        float pl = av[j] * als[lane];
        float pr = av[j] * ars[lane];
        for (int off = 32; off > 0; off >>= 1) {
            pl += __shfl_down(pl, off, 64);
            pr += __shfl_down(pr, off, 64);
        }
        if (lane == 0) { el[n0 + j] = pl; er[n0 + j] = pr; }
    }
}

// fused softmax + aggregation + bias + relu; one wave per dst node.
// No max subtraction (softmax shift-invariant; |e| << 88 so exp cannot overflow).
// Pass B: 4 lane-groups each gather one edge's feat row as float4 (4 edges in flight).
__global__ void gat_gather_kernel(const int* __restrict__ row_off, const int* __restrict__ csr_src,
                                  const float* __restrict__ el, const float* __restrict__ er,
                                  const float* __restrict__ feat, const float* __restrict__ b,
                                  float* __restrict__ out) {
    int wv = (blockIdx.x * blockDim.x + threadIdx.x) >> 6;
    int lane = threadIdx.x & 63;
    if (wv >= N_NODES) return;
    int beg = row_off[wv], end = row_off[wv + 1];
    int deg = end - beg;
    float ern = er[wv];
    int i0 = beg + lane;
    int s0 = (lane < deg) ? csr_src[i0] : 0;
    float w0 = (lane < deg) ? __expf(leaky02(el[s0] + ern)) : 0.f;
    float ls = w0;
    for (int i = i0 + 64; i < end; i += 64)            // rare: deg > 64
        ls += __expf(leaky02(el[csr_src[i]] + ern));
    for (int off = 32; off > 0; off >>= 1)
        ls += __shfl_xor(ls, off, 64);

    const float4* feat4 = (const float4*)feat;
    int grp = lane >> 4;          // edge slot within a 4-edge batch
    int sub = lane & 15;          // float4 index within the feature row
    float4 acc = make_float4(0.f, 0.f, 0.f, 0.f);
    int dmain = deg < 64 ? deg : 64;
    for (int ii = 0; ii < dmain; ii += 4) {
        int idx = ii + grp;
        int idxc = idx < dmain ? idx : dmain - 1;   // clamp (w forced to 0 below)
        int sE = __shfl(s0, idxc, 64);
        float w = __shfl(w0, idxc, 64);
        if (idx >= dmain) w = 0.f;
        float4 f = feat4[sE * 16 + sub];
        acc.x = fmaf(w, f.x, acc.x);
        acc.y = fmaf(w, f.y, acc.y);
        acc.z = fmaf(w, f.z, acc.z);
        acc.w = fmaf(w, f.w, acc.w);
    }
    for (int ii = 64 + grp; ii < deg; ii += 4) {       // rare: deg > 64
        int sE = csr_src[beg + ii];
        float w = __expf(leaky02(el[sE] + ern));
        float4 f = feat4[sE * 16 + sub];
        acc.x = fmaf(w, f.x, acc.x);
        acc.y = fmaf(w, f.y, acc.y);
        acc.z = fmaf(w, f.z, acc.z);
        acc.w = fmaf(w, f.w, acc.w);
    }
    // reduce the 4 edge-groups (lanes differing in bits 4,5 share the same sub)
    #pragma unroll
    for (int off = 16; off <= 32; off <<= 1) {
        acc.x += __shfl_xor(acc.x, off, 64);
        acc.y += __shfl_xor(acc.y, off, 64);
        acc.z += __shfl_xor(acc.z, off, 64);
        acc.w += __shfl_xor(acc.w, off, 64);
    }
    if (lane < 16) {
        float rls = (deg > 0) ? __frcp_rn(ls) : 0.f;
        float4 b4 = ((const float4*)b)[sub];
        float4 v;
        v.x = fmaxf(fmaf(acc.x, rls, b4.x), 0.f);
        v.y = fmaxf(fmaf(acc.y, rls, b4.y), 0.f);
        v.z = fmaxf(fmaf(acc.z, rls, b4.z), 0.f);
        v.w = fmaxf(fmaf(acc.w, rls, b4.w), 0.f);
        ((float4*)out)[wv * 16 + sub] = v;
    }
}

// graph_ids sorted: wave-chunked register accumulation, atomics only at transitions
#define POOL_WAVES 2048
__global__ void pool_kernel(const float* __restrict__ h, const int* __restrict__ gid,
                            float* __restrict__ hg, float* __restrict__ counts) {
    int gwave = (blockIdx.x * blockDim.x + threadIdx.x) >> 6;
    int lane = threadIdx.x & 63;
    const int chunk = (N_NODES + POOL_WAVES - 1) / POOL_WAVES;
    int start = gwave * chunk;
    int end = min(start + chunk, N_NODES);
    if (start >= end) return;
    int cur_g = gid[start];
    float acc = 0.f;
    float cnt = 0.f;
    for (int node = start; node < end; ++node) {
        int g = gid[node];
        if (g != cur_g) {
            atomicAdd(&hg[cur_g * H + lane], acc);
            if (lane == 0) atomicAdd(&counts[cur_g], cnt);
            acc = 0.f; cnt = 0.f; cur_g = g;
        }
        acc += h[node * H + lane];
        cnt += 1.f;
    }
    atomicAdd(&hg[cur_g * H + lane], acc);
    if (lane == 0) atomicAdd(&counts[cur_g], cnt);
}

__global__ void final_kernel(const float* __restrict__ hg, const float* __restrict__ counts,
                             const float* __restrict__ Wc, const float* __restrict__ bc,
                             float* __restrict__ out) {
    int g = blockIdx.x;
    int c = threadIdx.x;
    if (c >= CLS) return;
    float cnt = fmaxf(counts[g], 1.0f);
    float acc = 0.f;
    for (int j = 0; j < H; ++j) acc += hg[g * H + j] * Wc[j * CLS + c];
    out[g * CLS + c] = acc / cnt + bc[c];
}

extern "C" void kernel_launch(void* const* d_in, const int* in_sizes, int n_in,
                              void* d_out, int out_size, void* d_ws, size_t ws_size,
                              hipStream_t stream) {
    const int* src = (const int*)d_in[0];
    const int* dst = (const int*)d_in[1];
    const int* gid = (const int*)d_in[2];
    const float* W1 = (const float*)d_in[3];
    const float* al1 = (const float*)d_in[4];
    const float* ar1 = (const float*)d_in[5];
    const float* b1 = (const float*)d_in[6];
    const float* W2 = (const float*)d_in[7];
    const float* al2 = (const float*)d_in[8];
    const float* ar2 = (const float*)d_in[9];
    const float* b2 = (const float*)d_in[10];
    const float* W3 = (const float*)d_in[11];
    const float* al3 = (const float*)d_in[12];
    const float* ar3 = (const float*)d_in[13];
    const float* b3 = (const float*)d_in[14];
    const float* Wc = (const float*)d_in[15];
    const float* bc = (const float*)d_in[16];
    float* out = (float*)d_out;

    float* ws = (float*)d_ws;
    float* bufA = ws;                          // N*H  (h)
    float* bufB = bufA + (size_t)N_NODES * H;  // N*H  (feat)
    float* el = bufB + (size_t)N_NODES * H;    // N
    float* er = el + N_NODES;                  // N
    float* hg = er + N_NODES;                  // G*H
    float* counts = hg + G_GRAPHS * H;         // G
    int* row_off = (int*)(counts + G_GRAPHS);  // N+1
    int* cnt = row_off + N_NODES + 1;          // N
    int* bsum = cnt + N_NODES;                 // NB
    int* csr_src = bsum + NB;                  // E

    const float* Warr[3] = {W1, W2, W3};
    const float* alarr[3] = {al1, al2, al3};
    const float* ararr[3] = {ar1, ar2, ar3};
    const float* barr[3] = {b1, b2, b3};

    int eblocks = (N_EDGES + 255) / 256;
    int nblocks4 = (N_NODES + 3) / 4;

    // ---- build CSR by dst ----
    fill_i_kernel<<<256, 256, 0, stream>>>(cnt, 0, N_NODES);
    count_kernel<<<eblocks, 256, 0, stream>>>(dst, cnt);
    scanA_kernel<<<NB, 256, 0, stream>>>(cnt, bsum);
    scanC_kernel<<<NB, 256, 0, stream>>>(cnt, bsum, row_off);
    scatter_kernel<<<eblocks, 256, 0, stream>>>(src, dst, row_off, cnt, csr_src);

    // ---- 3 GAT layers ----
    for (int layer = 0; layer < 3; ++layer) {
        if (layer == 0) {
            feat1_kernel<<<nblocks4, 256, 0, stream>>>(row_off, Warr[0], alarr[0],
                                                       ararr[0], bufB, el, er);
        } else {
            feat64_kernel<<<N_NODES / 16, 256, 0, stream>>>(bufA, Warr[layer], alarr[layer],
                                                            ararr[layer], bufB, el, er);
        }
        gat_gather_kernel<<<nblocks4, 256, 0, stream>>>(row_off, csr_src, el, er, bufB,
                                                        barr[layer], bufA);
    }

    // ---- pooling + classifier ----
    fill_f_kernel<<<1, 256, 0, stream>>>(hg, 0.f, G_GRAPHS * H + G_GRAPHS);
    pool_kernel<<<POOL_WAVES / 4, 256, 0, stream>>>(bufA, gid, hg, counts);
    final_kernel<<<G_GRAPHS, 64, 0, stream>>>(hg, counts, Wc, bc, out);
}